// Round 1
// baseline (122.989 us; speedup 1.0000x reference)
//
#include <hip/hip_runtime.h>

// ---------------------------------------------------------------------------
// R13: FUSED single kernel, ZERO workspace use.
//
// Theory: the 88.8 us timing is dominated by two ~41 us 256 MiB
// __amd_rocclr_fillBufferAligned dispatches (harness workspace re-poison,
// the top-5 dispatches at 81% HBM peak). Our own kernels are ~13 us total
// (neither appears in top-5, i.e. each < 40.7 us). Eliminating all d_ws
// use tests whether the poison leaves the timed region.
//
// Per block = one 32x32 tile pair (bi<=bj), grid 4*136 = 544:
//   Phase A: stage Xi,Xj (32x128 f32) in LDS; per-block GEMMs
//            Ha = Xi*W1c[0:128] + b1c   (acc[4][4]/thread, rt/ct map)
//            Hb = Xj*W1c[128:256]
//            diag blocks: Hs = Xi*W1s + b1s reduced IN REGISTERS
//            (relu . W2s, shfl_xor over 32 lanes) -> dg[32].
//            W streamed via transposed LDS chunk Wt[128][36], KT=32.
//            Ha/Hb overwrite the X buffers (after sync).
//   Phase C: R12's proven pair loop, but f32 LDS (no bf16 unpack);
//            h never round-trips through bf16 -> absmax should drop.
// LDS: 2*4224 + 4608 + 288 floats = 52.1 KB -> 3 blocks/CU.
// ---------------------------------------------------------------------------

__device__ __forceinline__ void gemm32x128(
    const float* __restrict__ Wg,     // [128][128] row-major (k, col)
    const float* __restrict__ biasg,  // [128] or nullptr
    const float* bufX,                // LDS [32][132] input rows
    float* Wt,                        // LDS [128][36] scratch (transposed W)
    int t, float acc[4][4])
{
    const int rt = t >> 5;   // 0..7   -> rows rt + 8i
    const int ct = t & 31;   // 0..31  -> cols ct + 32j

#pragma unroll
    for (int j = 0; j < 4; ++j) {
        const float bv = biasg ? biasg[ct + 32 * j] : 0.f;
#pragma unroll
        for (int i = 0; i < 4; ++i) acc[i][j] = bv;
    }

    for (int kc = 0; kc < 4; ++kc) {
        const int k0 = kc * 32;
        __syncthreads();                      // Wt free to overwrite
#pragma unroll
        for (int q = 0; q < 4; ++q) {
            const int f  = t + q * 256;
            const int kr = f & 31;            // lane-major k rows
            const int c4 = f >> 5;            // -> ~2-way LDS store aliasing
            float4 w = *(const float4*)(Wg + (size_t)(k0 + kr) * 128 + c4 * 4);
            Wt[(c4 * 4 + 0) * 36 + kr] = w.x;
            Wt[(c4 * 4 + 1) * 36 + kr] = w.y;
            Wt[(c4 * 4 + 2) * 36 + kr] = w.z;
            Wt[(c4 * 4 + 3) * 36 + kr] = w.w;
        }
        __syncthreads();
#pragma unroll
        for (int kk = 0; kk < 32; kk += 8) {
            float xa[4][8], wb[4][8];
#pragma unroll
            for (int i = 0; i < 4; ++i) {
                const float* p = bufX + (rt + 8 * i) * 132 + k0 + kk;
                float4 a0 = *(const float4*)p;
                float4 a1 = *(const float4*)(p + 4);
                xa[i][0]=a0.x; xa[i][1]=a0.y; xa[i][2]=a0.z; xa[i][3]=a0.w;
                xa[i][4]=a1.x; xa[i][5]=a1.y; xa[i][6]=a1.z; xa[i][7]=a1.w;
            }
#pragma unroll
            for (int j = 0; j < 4; ++j) {
                const float* p = Wt + (ct + 32 * j) * 36 + kk;
                float4 b0 = *(const float4*)p;
                float4 b1 = *(const float4*)(p + 4);
                wb[j][0]=b0.x; wb[j][1]=b0.y; wb[j][2]=b0.z; wb[j][3]=b0.w;
                wb[j][4]=b1.x; wb[j][5]=b1.y; wb[j][6]=b1.z; wb[j][7]=b1.w;
            }
#pragma unroll
            for (int e = 0; e < 8; ++e)
#pragma unroll
                for (int i = 0; i < 4; ++i)
#pragma unroll
                    for (int j = 0; j < 4; ++j)
                        acc[i][j] += xa[i][e] * wb[j][e];
        }
    }
}

__global__ __launch_bounds__(256) void fused_pair(
    const float* __restrict__ X,
    const float* __restrict__ W1c, const float* __restrict__ b1c,
    const float* __restrict__ W2c, const float* __restrict__ b2c,
    const float* __restrict__ W1s, const float* __restrict__ b1s,
    const float* __restrict__ W2s, const float* __restrict__ b2s,
    float* __restrict__ out)
{
    __shared__ float bufA[32 * 132];   // Xi -> Ha
    __shared__ float bufB[32 * 132];   // Xj -> Hb
    __shared__ float Wt[128 * 36];     // W chunk (transposed); later T overlay
    __shared__ float w2l[128];
    __shared__ float w2sl[128];
    __shared__ float dg[32];

    const int t  = threadIdx.x;
    const int b  = blockIdx.x / 136;
    const int rr = blockIdx.x % 136;
    int bj = (int)((sqrtf(8.f * rr + 1.f) - 1.f) * 0.5f);
    while ((bj + 1) * (bj + 2) / 2 <= rr) ++bj;
    while (bj * (bj + 1) / 2 > rr) --bj;
    const int bi = rr - bj * (bj + 1) / 2;          // bi <= bj
    const bool isdiag = (bi == bj);

    const float* Xi = X + (size_t)(b * 512 + bi * 32) * 128;
    const float* Xj = X + (size_t)(b * 512 + bj * 32) * 128;

    // stage Xi, Xj (coalesced float4; diag: Xj==Xi, harmless double copy)
#pragma unroll
    for (int q = 0; q < 4; ++q) {
        const int idx = t + q * 256;
        const int r = idx >> 5, k4 = idx & 31;
        *(float4*)(bufA + r * 132 + k4 * 4) =
            *(const float4*)(Xi + (size_t)r * 128 + k4 * 4);
        *(float4*)(bufB + r * 132 + k4 * 4) =
            *(const float4*)(Xj + (size_t)r * 128 + k4 * 4);
    }
    if (t < 128) w2l[t] = W2c[t];
    else         w2sl[t - 128] = W2s[t - 128];
    // (first __syncthreads inside gemm32x128 covers these stores)

    const int rt = t >> 5, ct = t & 31;
    float acc[4][4];

    if (isdiag) {
        // Hs = Xi*W1s + b1s, reduced in-register: dg[i] = sigmoid(sum_h relu*W2s + b2s)
        gemm32x128(W1s, b1s, bufA, Wt, t, acc);
        float p[4];
#pragma unroll
        for (int i = 0; i < 4; ++i) {
            float s = 0.f;
#pragma unroll
            for (int j = 0; j < 4; ++j)
                s += fmaxf(acc[i][j], 0.f) * w2sl[ct + 32 * j];
            p[i] = s;
        }
#pragma unroll
        for (int i = 0; i < 4; ++i) {
            p[i] += __shfl_xor(p[i], 1);
            p[i] += __shfl_xor(p[i], 2);
            p[i] += __shfl_xor(p[i], 4);
            p[i] += __shfl_xor(p[i], 8);
            p[i] += __shfl_xor(p[i], 16);
        }
        if (ct == 0) {
            const float b2s0 = b2s[0];
#pragma unroll
            for (int i = 0; i < 4; ++i)
                dg[rt + 8 * i] = 1.f / (1.f + __expf(-(p[i] + b2s0)));
        }
    }

    // Ha = Xi * W1c[0:128] + b1c
    gemm32x128(W1c, b1c, bufA, Wt, t, acc);
    __syncthreads();                               // all reads of Xi done
#pragma unroll
    for (int i = 0; i < 4; ++i)
#pragma unroll
        for (int j = 0; j < 4; ++j)
            bufA[(rt + 8 * i) * 132 + ct + 32 * j] = acc[i][j];

    // Hb = Xj * W1c[128:256]
    gemm32x128(W1c + 128 * 128, nullptr, bufB, Wt, t, acc);
    __syncthreads();                               // all reads of Xj done
#pragma unroll
    for (int i = 0; i < 4; ++i)
#pragma unroll
        for (int j = 0; j < 4; ++j)
            bufB[(rt + 8 * i) * 132 + ct + 32 * j] = acc[i][j];
    __syncthreads();                               // Ha/Hb visible

    // -------------------- Phase C: pair loop (R12 structure, f32) ----------
    const int tx = t & 15, ty = t >> 4;
    float acc2[2][2] = {{0.f, 0.f}, {0.f, 0.f}};

    for (int kk = 0; kk < 128; kk += 8) {
        float wv[8];
        {
            float4 w0 = *(const float4*)(w2l + kk);
            float4 w1 = *(const float4*)(w2l + kk + 4);
            wv[0]=w0.x; wv[1]=w0.y; wv[2]=w0.z; wv[3]=w0.w;
            wv[4]=w1.x; wv[5]=w1.y; wv[6]=w1.z; wv[7]=w1.w;
        }
        float av[2][8], bv[2][8];
#pragma unroll
        for (int r = 0; r < 2; ++r) {
            const float* p = bufA + (ty + 16 * r) * 132 + kk;
            float4 a0 = *(const float4*)p;
            float4 a1 = *(const float4*)(p + 4);
            av[r][0]=a0.x; av[r][1]=a0.y; av[r][2]=a0.z; av[r][3]=a0.w;
            av[r][4]=a1.x; av[r][5]=a1.y; av[r][6]=a1.z; av[r][7]=a1.w;
        }
#pragma unroll
        for (int s = 0; s < 2; ++s) {
            const float* p = bufB + (tx + 16 * s) * 132 + kk;
            float4 b0 = *(const float4*)p;
            float4 b1 = *(const float4*)(p + 4);
            bv[s][0]=b0.x; bv[s][1]=b0.y; bv[s][2]=b0.z; bv[s][3]=b0.w;
            bv[s][4]=b1.x; bv[s][5]=b1.y; bv[s][6]=b1.z; bv[s][7]=b1.w;
        }
#pragma unroll
        for (int e = 0; e < 8; ++e)
#pragma unroll
            for (int r = 0; r < 2; ++r)
#pragma unroll
                for (int s = 0; s < 2; ++s)
                    acc2[r][s] += fmaxf(av[r][e] + bv[s][e], 0.f) * wv[e];
    }

    const float bias2 = b2c[0];
    float val[2][2];
#pragma unroll
    for (int r = 0; r < 2; ++r)
#pragma unroll
        for (int s = 0; s < 2; ++s)
            val[r][s] = 1.f / (1.f + __expf(-(acc2[r][s] + bias2)));

    // transpose tile for coalesced mirror stores (overlay on Wt; Wt is dead)
    float* T = Wt;
#pragma unroll
    for (int r = 0; r < 2; ++r)
#pragma unroll
        for (int s = 0; s < 2; ++s)
            T[(ty + 16 * r) * 33 + (tx + 16 * s)] = val[r][s];
    __syncthreads();

    float* outb = out + ((size_t)b << 18);

    if (!isdiag) {
        // direct stores (upper tile)
#pragma unroll
        for (int r = 0; r < 2; ++r) {
            const int i = bi * 32 + ty + 16 * r;
#pragma unroll
            for (int s = 0; s < 2; ++s) {
                const int j = bj * 32 + tx + 16 * s;
                outb[i * 512 + j] = val[r][s];
            }
        }
        // mirror stores (lower tile), coalesced via T
#pragma unroll
        for (int r = 0; r < 2; ++r) {
            const int a  = ty + 16 * r;
            const int i2 = bj * 32 + a;
#pragma unroll
            for (int s = 0; s < 2; ++s) {
                const int bb = tx + 16 * s;
                const int j2 = bi * 32 + bb;
                outb[i2 * 512 + j2] = T[bb * 33 + a];
            }
        }
    } else {
#pragma unroll
        for (int r = 0; r < 2; ++r) {
            const int li = ty + 16 * r;
            const int i  = bi * 32 + li;
#pragma unroll
            for (int s = 0; s < 2; ++s) {
                const int lj = tx + 16 * s;
                const int j  = bj * 32 + lj;
                float v;
                if (li < lj)      v = val[r][s];
                else if (li > lj) v = T[lj * 33 + li];
                else              v = dg[li];
                outb[i * 512 + j] = v;
            }
        }
    }
}

// ---------------------------------------------------------------------------
extern "C" void kernel_launch(void* const* d_in, const int* in_sizes, int n_in,
                              void* d_out, int out_size, void* d_ws, size_t ws_size,
                              hipStream_t stream) {
    const float* X   = (const float*)d_in[0];
    const float* W1c = (const float*)d_in[1];
    const float* b1c = (const float*)d_in[2];
    const float* W2c = (const float*)d_in[3];
    const float* b2c = (const float*)d_in[4];
    const float* W1s = (const float*)d_in[5];
    const float* b1s = (const float*)d_in[6];
    const float* W2s = (const float*)d_in[7];
    const float* b2s = (const float*)d_in[8];

    float* out = (float*)d_out;                // [4][512][512] fp32

    // NOTE: d_ws deliberately untouched (hypothesis: ws re-poison fills
    // dominate the timed region).
    (void)d_ws; (void)ws_size;

    fused_pair<<<544, 256, 0, stream>>>(X, W1c, b1c, W2c, b2c,
                                        W1s, b1s, W2s, b2s, out);
}

// Round 2
// 86.443 us; speedup vs baseline: 1.4228x; 1.4228x over previous
//
#include <hip/hip_runtime.h>

// ---------------------------------------------------------------------------
// R14: zero-workspace fused kernel, H-GEMMs moved to MFMA (bf16).
//
// R13 post-mortem: fused VALU kernel = 63 us, VALUBusy 27%, MfmaUtil 0,
// 2.96M LDS bank-conflict cycles. The per-block recompute of
// Ha/Hb/(Hs) (571M FMAs chip-wide) on the vector ALU plus 12+ syncthreads
// of chunked Wt staging is the bottleneck.
//
// R14: per block (b, bi<=bj tile pair):
//   - stage Xi,Xj f32 in LDS (bufA/bufB, pitch 132)
//   - Ha = Xi*W1c[0:128]+b1c, Hb = Xj*W1c[128:256] via
//     v_mfma_f32_16x16x32_bf16: A-frags from LDS f32 + v_cvt_pk_bf16_f32,
//     B-frags loaded per-lane strided straight from global W (L2-hot),
//     4 waves each own a 32-col strip. 16 MFMAs per GEMM per wave.
//   - diag blocks: Hs = Xi*W1s+b1s same way, reduced in-register
//     (relu . W2s, shfl_xor over the 16-lane col groups) -> dg[32].
//   - overwrite bufA/bufB with f32 Ha/Hb, then run the PROVEN R12/R13
//     phase-C pair loop + transpose-tile mirror stores.
// Syncs: 4 (off-diag) / 5 (diag) vs R13's 12-16.
// LDS: 2*16896 + 512 + 4224 + 512 + 128 = 39.2 KB -> 4 blocks/CU capacity.
// MFMA frag layouts (guide-verified): A row=l&15,k=(l>>4)*8+e;
// B col=l&15,k=(l>>4)*8+e; D col=l&15,row=(l>>4)*4+q.
// ---------------------------------------------------------------------------

typedef __attribute__((ext_vector_type(8))) short short8v;  // 8 bf16
typedef __attribute__((ext_vector_type(4))) float f32x4;

__device__ __forceinline__ unsigned cvt2bf(float lo, float hi) {
    unsigned r;
    asm("v_cvt_pk_bf16_f32 %0, %1, %2" : "=v"(r) : "v"(lo), "v"(hi));
    return r;
}

__device__ __forceinline__ short8v pack8(float4 a, float4 b) {
    union { unsigned u[4]; short8v v; } x;
    x.u[0] = cvt2bf(a.x, a.y);
    x.u[1] = cvt2bf(a.z, a.w);
    x.u[2] = cvt2bf(b.x, b.y);
    x.u[3] = cvt2bf(b.z, b.w);
    return x.v;
}

// H[32][128] (f32 acc) = bf16(buf[32][128]) * bf16(Wg[128][128]); per-wave
// 32-col strip n0. acc[mi][ni][q] = H[mi*16 + l4*4 + q][n0 + ni*16 + l15].
__device__ __forceinline__ void mfma_gemm32(
    const float* buf,                 // LDS [32][132] f32 rows
    const float* __restrict__ Wg,     // global [128][128] f32, k-major
    int l15, int l4, int n0,
    f32x4 acc[2][2])
{
#pragma unroll
    for (int mi = 0; mi < 2; ++mi)
#pragma unroll
        for (int ni = 0; ni < 2; ++ni)
            acc[mi][ni] = f32x4{0.f, 0.f, 0.f, 0.f};

#pragma unroll
    for (int ks = 0; ks < 4; ++ks) {
        const int kb = ks * 32 + l4 * 8;
        short8v a[2], bb[2];
#pragma unroll
        for (int mi = 0; mi < 2; ++mi) {
            const float* p = buf + (mi * 16 + l15) * 132 + kb;
            a[mi] = pack8(*(const float4*)p, *(const float4*)(p + 4));
        }
#pragma unroll
        for (int ni = 0; ni < 2; ++ni) {
            const float* p = Wg + (size_t)kb * 128 + n0 + ni * 16 + l15;
            float f0 = p[0],   f1 = p[128], f2 = p[256], f3 = p[384];
            float f4 = p[512], f5 = p[640], f6 = p[768], f7 = p[896];
            union { unsigned u[4]; short8v v; } x;
            x.u[0] = cvt2bf(f0, f1); x.u[1] = cvt2bf(f2, f3);
            x.u[2] = cvt2bf(f4, f5); x.u[3] = cvt2bf(f6, f7);
            bb[ni] = x.v;
        }
#pragma unroll
        for (int mi = 0; mi < 2; ++mi)
#pragma unroll
            for (int ni = 0; ni < 2; ++ni)
                acc[mi][ni] = __builtin_amdgcn_mfma_f32_16x16x32_bf16(
                    a[mi], bb[ni], acc[mi][ni], 0, 0, 0);
    }
}

__device__ __forceinline__ void store_h(
    float* buf, const f32x4 acc[2][2], int l15, int l4, int n0,
    const float* __restrict__ bias)   // nullable
{
    float bv[2] = {0.f, 0.f};
    if (bias) { bv[0] = bias[n0 + l15]; bv[1] = bias[n0 + 16 + l15]; }
#pragma unroll
    for (int mi = 0; mi < 2; ++mi)
#pragma unroll
        for (int ni = 0; ni < 2; ++ni)
#pragma unroll
            for (int q = 0; q < 4; ++q)
                buf[(mi * 16 + l4 * 4 + q) * 132 + n0 + ni * 16 + l15]
                    = acc[mi][ni][q] + bv[ni];
}

__global__ __launch_bounds__(256) void fused_pair(
    const float* __restrict__ X,
    const float* __restrict__ W1c, const float* __restrict__ b1c,
    const float* __restrict__ W2c, const float* __restrict__ b2c,
    const float* __restrict__ W1s, const float* __restrict__ b1s,
    const float* __restrict__ W2s, const float* __restrict__ b2s,
    float* __restrict__ out)
{
    __shared__ float bufA[32 * 132];   // Xi -> Ha (f32)
    __shared__ float bufB[32 * 132];   // Xj -> Hb (f32)
    __shared__ float w2l[128];
    __shared__ float T[32 * 33];
    __shared__ float dred[128];        // 4 waves x 32 rows (diag)
    __shared__ float dg[32];

    const int t  = threadIdx.x;
    const int b  = blockIdx.x / 136;
    const int rr = blockIdx.x % 136;
    int bj = (int)((sqrtf(8.f * rr + 1.f) - 1.f) * 0.5f);
    while ((bj + 1) * (bj + 2) / 2 <= rr) ++bj;
    while (bj * (bj + 1) / 2 > rr) --bj;
    const int bi = rr - bj * (bj + 1) / 2;          // bi <= bj
    const bool isdiag = (bi == bj);

    const float* Xi = X + (size_t)(b * 512 + bi * 32) * 128;
    const float* Xj = X + (size_t)(b * 512 + bj * 32) * 128;

    // stage Xi, Xj (coalesced float4)
#pragma unroll
    for (int q = 0; q < 4; ++q) {
        const int idx = t + q * 256;
        const int r = idx >> 5, k4 = idx & 31;
        *(float4*)(bufA + r * 132 + k4 * 4) =
            *(const float4*)(Xi + (size_t)r * 128 + k4 * 4);
        *(float4*)(bufB + r * 132 + k4 * 4) =
            *(const float4*)(Xj + (size_t)r * 128 + k4 * 4);
    }
    if (t < 128) w2l[t] = W2c[t];
    __syncthreads();                                   // [1]

    const int lane = t & 63;
    const int w    = t >> 6;          // wave 0..3
    const int n0   = w * 32;
    const int l15  = lane & 15, l4 = lane >> 4;

    if (isdiag) {
        // Hs = Xi*W1s + b1s; dg[i] = sigmoid(b2s + sum_h relu(Hs)*W2s)
        f32x4 accS[2][2];
        mfma_gemm32(bufA, W1s, l15, l4, n0, accS);
        const float w2sv[2] = {W2s[n0 + l15], W2s[n0 + 16 + l15]};
        const float b1sv[2] = {b1s[n0 + l15], b1s[n0 + 16 + l15]};
        float pr[2][4];
#pragma unroll
        for (int mi = 0; mi < 2; ++mi)
#pragma unroll
            for (int q = 0; q < 4; ++q)
                pr[mi][q] = fmaxf(accS[mi][0][q] + b1sv[0], 0.f) * w2sv[0]
                          + fmaxf(accS[mi][1][q] + b1sv[1], 0.f) * w2sv[1];
        // reduce across the 16-lane col group
#pragma unroll
        for (int mi = 0; mi < 2; ++mi)
#pragma unroll
            for (int q = 0; q < 4; ++q) {
                pr[mi][q] += __shfl_xor(pr[mi][q], 1);
                pr[mi][q] += __shfl_xor(pr[mi][q], 2);
                pr[mi][q] += __shfl_xor(pr[mi][q], 4);
                pr[mi][q] += __shfl_xor(pr[mi][q], 8);
            }
        if (l15 == 0) {
#pragma unroll
            for (int mi = 0; mi < 2; ++mi)
#pragma unroll
                for (int q = 0; q < 4; ++q)
                    dred[w * 32 + mi * 16 + l4 * 4 + q] = pr[mi][q];
        }
        __syncthreads();                               // [2]
        if (t < 32) {
            float s = b2s[0] + dred[t] + dred[32 + t] + dred[64 + t] + dred[96 + t];
            dg[t] = 1.f / (1.f + __expf(-s));
        }
    }

    // Ha = Xi*W1c[0:128]+b1c ; Hb = Xj*W1c[128:256]
    f32x4 accA[2][2], accB[2][2];
    mfma_gemm32(bufA, W1c,             l15, l4, n0, accA);
    mfma_gemm32(bufB, W1c + 128 * 128, l15, l4, n0, accB);
    __syncthreads();                                   // [3] all X reads done
    store_h(bufA, accA, l15, l4, n0, b1c);
    store_h(bufB, accB, l15, l4, n0, nullptr);
    __syncthreads();                                   // [4] H visible

    // -------------------- Phase C: pair loop (proven) ----------------------
    const int tx = t & 15, ty = t >> 4;
    float acc2[2][2] = {{0.f, 0.f}, {0.f, 0.f}};

    for (int kk = 0; kk < 128; kk += 8) {
        float wv[8];
        {
            float4 w0 = *(const float4*)(w2l + kk);
            float4 w1 = *(const float4*)(w2l + kk + 4);
            wv[0]=w0.x; wv[1]=w0.y; wv[2]=w0.z; wv[3]=w0.w;
            wv[4]=w1.x; wv[5]=w1.y; wv[6]=w1.z; wv[7]=w1.w;
        }
        float av[2][8], bv[2][8];
#pragma unroll
        for (int r = 0; r < 2; ++r) {
            const float* p = bufA + (ty + 16 * r) * 132 + kk;
            float4 a0 = *(const float4*)p;
            float4 a1 = *(const float4*)(p + 4);
            av[r][0]=a0.x; av[r][1]=a0.y; av[r][2]=a0.z; av[r][3]=a0.w;
            av[r][4]=a1.x; av[r][5]=a1.y; av[r][6]=a1.z; av[r][7]=a1.w;
        }
#pragma unroll
        for (int s = 0; s < 2; ++s) {
            const float* p = bufB + (tx + 16 * s) * 132 + kk;
            float4 b0 = *(const float4*)p;
            float4 b1 = *(const float4*)(p + 4);
            bv[s][0]=b0.x; bv[s][1]=b0.y; bv[s][2]=b0.z; bv[s][3]=b0.w;
            bv[s][4]=b1.x; bv[s][5]=b1.y; bv[s][6]=b1.z; bv[s][7]=b1.w;
        }
#pragma unroll
        for (int e = 0; e < 8; ++e)
#pragma unroll
            for (int r = 0; r < 2; ++r)
#pragma unroll
                for (int s = 0; s < 2; ++s)
                    acc2[r][s] += fmaxf(av[r][e] + bv[s][e], 0.f) * wv[e];
    }

    const float bias2 = b2c[0];
    float val[2][2];
#pragma unroll
    for (int r = 0; r < 2; ++r)
#pragma unroll
        for (int s = 0; s < 2; ++s)
            val[r][s] = 1.f / (1.f + __expf(-(acc2[r][s] + bias2)));

    // transpose tile for coalesced mirror stores
#pragma unroll
    for (int r = 0; r < 2; ++r)
#pragma unroll
        for (int s = 0; s < 2; ++s)
            T[(ty + 16 * r) * 33 + (tx + 16 * s)] = val[r][s];
    __syncthreads();                                   // [5]

    float* outb = out + ((size_t)b << 18);

    if (!isdiag) {
#pragma unroll
        for (int r = 0; r < 2; ++r) {
            const int i = bi * 32 + ty + 16 * r;
#pragma unroll
            for (int s = 0; s < 2; ++s) {
                const int j = bj * 32 + tx + 16 * s;
                outb[i * 512 + j] = val[r][s];
            }
        }
#pragma unroll
        for (int r = 0; r < 2; ++r) {
            const int a2 = ty + 16 * r;
            const int i2 = bj * 32 + a2;
#pragma unroll
            for (int s = 0; s < 2; ++s) {
                const int bb2 = tx + 16 * s;
                const int j2  = bi * 32 + bb2;
                outb[i2 * 512 + j2] = T[bb2 * 33 + a2];
            }
        }
    } else {
#pragma unroll
        for (int r = 0; r < 2; ++r) {
            const int li = ty + 16 * r;
            const int i  = bi * 32 + li;
#pragma unroll
            for (int s = 0; s < 2; ++s) {
                const int lj = tx + 16 * s;
                const int j  = bj * 32 + lj;
                float v;
                if (li < lj)      v = val[r][s];
                else if (li > lj) v = T[lj * 33 + li];
                else              v = dg[li];
                outb[i * 512 + j] = v;
            }
        }
    }
}

// ---------------------------------------------------------------------------
extern "C" void kernel_launch(void* const* d_in, const int* in_sizes, int n_in,
                              void* d_out, int out_size, void* d_ws, size_t ws_size,
                              hipStream_t stream) {
    const float* X   = (const float*)d_in[0];
    const float* W1c = (const float*)d_in[1];
    const float* b1c = (const float*)d_in[2];
    const float* W2c = (const float*)d_in[3];
    const float* b2c = (const float*)d_in[4];
    const float* W1s = (const float*)d_in[5];
    const float* b1s = (const float*)d_in[6];
    const float* W2s = (const float*)d_in[7];
    const float* b2s = (const float*)d_in[8];

    float* out = (float*)d_out;                // [4][512][512] fp32

    // d_ws deliberately untouched (ws re-poison avoidance, confirmed R13).
    (void)d_ws; (void)ws_size;

    fused_pair<<<544, 256, 0, stream>>>(X, W1c, b1c, W2c, b2c,
                                        W1s, b1s, W2s, b2s, out);
}